// Round 1
// baseline (507.361 us; speedup 1.0000x reference)
//
#include <hip/hip_runtime.h>

// out[B=16384, ONUM=512] = x[B, INUM=4096] @ wB[ONUM, INUM]^T, wB = (u < weight)
// Strategy: binarize wB -> bf16 {0,1} in d_ws (exact), cast x -> bf16 on the fly
// (error ~0.2 absmax << 22.56 threshold), mfma_f32_16x16x32_bf16 GEMM.

#define M_DIM 16384
#define N_DIM 512
#define K_DIM 4096
#define BM 128
#define BN 128
#define BK 64

using bf16x8 = __attribute__((ext_vector_type(8))) short;
using f32x4  = __attribute__((ext_vector_type(4))) float;

typedef __attribute__((address_space(1))) const void glb_cv;
typedef __attribute__((address_space(3))) void lds_v;

__device__ __forceinline__ unsigned short f2bf(float f) {
    union { float f; unsigned int u; } v;
    v.f = f;
    unsigned int r = v.u + 0x7FFFu + ((v.u >> 16) & 1u);   // RNE
    return (unsigned short)(r >> 16);
}

// ---------------- binarize: wB[o,k] = (u < weight) ? 1.0bf16 : 0 ----------------
__global__ __launch_bounds__(256) void binarize_kernel(const float* __restrict__ w,
                                                       const float* __restrict__ u,
                                                       unsigned short* __restrict__ wb) {
    int i = (blockIdx.x * 256 + threadIdx.x) * 4;   // grid sized exactly: N_DIM*K_DIM/4 threads
    float4 wv = *(const float4*)(w + i);
    float4 uv = *(const float4*)(u + i);
    ushort4 o;
    o.x = (uv.x < wv.x) ? 0x3F80u : 0u;
    o.y = (uv.y < wv.y) ? 0x3F80u : 0u;
    o.z = (uv.z < wv.z) ? 0x3F80u : 0u;
    o.w = (uv.w < wv.w) ? 0x3F80u : 0u;
    *(ushort4*)(wb + i) = o;
}

// ---------------- GEMM: 128x128 tile, BK=64, 4 waves (2x2), 4x4 frags/wave ----------------
__global__ __launch_bounds__(256) void gemm_bin_kernel(const float* __restrict__ x,
                                                       const unsigned short* __restrict__ wb,
                                                       float* __restrict__ out) {
    __shared__ unsigned short As[BM][72];        // padded stride 144B (16B-aligned rows)
    __shared__ unsigned short Bs[BN][BK];        // unpadded: global_load_lds contiguity

    const int t    = threadIdx.x;
    const int lane = t & 63;
    const int wave = t >> 6;
    const int bn   = blockIdx.x;                 // N tile (fastest -> x-tile LLC reuse)
    const int bm   = blockIdx.y;                 // M tile

    const int wm = (wave & 1) * 64;              // wave origin in block tile
    const int wn = (wave >> 1) * 64;

    f32x4 acc[4][4] = {};

    // A staging map: per j, 16 rows; thread t -> row j*16 + (t>>4), col (t&15)*4 floats
    const int arow = t >> 4;
    const int acol = (t & 15) * 4;
    const float* xg = x + (size_t)(bm * BM) * K_DIM;
    const unsigned short* wbg = wb + (size_t)(bn * BN) * K_DIM;

    for (int k0 = 0; k0 < K_DIM; k0 += BK) {
        // ---- stage A: 128x64 fp32 -> bf16 -> LDS ----
        const float* ag = xg + k0;
#pragma unroll
        for (int j = 0; j < 8; ++j) {
            int r = j * 16 + arow;
            float4 v = *(const float4*)(ag + (size_t)r * K_DIM + acol);
            ushort4 h;
            h.x = f2bf(v.x); h.y = f2bf(v.y); h.z = f2bf(v.z); h.w = f2bf(v.w);
            *(ushort4*)(&As[r][acol]) = h;
        }
        // ---- stage B: 128x64 bf16 via global_load_lds (16B/lane) ----
#pragma unroll
        for (int c = 0; c < 4; ++c) {
            int e  = c * 256 + t;                // 16B chunk index
            int rb = e >> 3;                     // row in tile (64 bf16 = 8 chunks)
            int cb = (e & 7) * 8;                // bf16 col
            const unsigned short* gsrc = wbg + (size_t)rb * K_DIM + k0 + cb;
            unsigned short* ldst = (unsigned short*)Bs + (size_t)e * 8;
            __builtin_amdgcn_global_load_lds((glb_cv*)(const void*)gsrc,
                                             (lds_v*)(void*)ldst, 16, 0, 0);
        }
        __syncthreads();

        // ---- compute: 2 k-steps of 32 ----
#pragma unroll
        for (int kk = 0; kk < 2; ++kk) {
            const int krow = kk * 32 + (lane >> 4) * 8;
            bf16x8 af[4], bfr[4];
#pragma unroll
            for (int i = 0; i < 4; ++i)
                af[i] = *(const bf16x8*)(&As[wm + i * 16 + (lane & 15)][krow]);
#pragma unroll
            for (int i = 0; i < 4; ++i)
                bfr[i] = *(const bf16x8*)(&Bs[wn + i * 16 + (lane & 15)][krow]);
#pragma unroll
            for (int i = 0; i < 4; ++i)
#pragma unroll
                for (int j = 0; j < 4; ++j)
                    acc[i][j] = __builtin_amdgcn_mfma_f32_16x16x32_bf16(af[i], bfr[j], acc[i][j], 0, 0, 0);
        }
        __syncthreads();
    }

    // ---- epilogue: C/D layout col=lane&15, row=(lane>>4)*4+reg ----
    const int col0 = bn * BN + wn + (lane & 15);
    const int row0 = bm * BM + wm + (lane >> 4) * 4;
#pragma unroll
    for (int i = 0; i < 4; ++i)
#pragma unroll
        for (int j = 0; j < 4; ++j)
#pragma unroll
            for (int r = 0; r < 4; ++r)
                out[(size_t)(row0 + i * 16 + r) * N_DIM + (col0 + j * 16)] = acc[i][j][r];
}

extern "C" void kernel_launch(void* const* d_in, const int* in_sizes, int n_in,
                              void* d_out, int out_size, void* d_ws, size_t ws_size,
                              hipStream_t stream) {
    const float* x = (const float*)d_in[0];
    const float* w = (const float*)d_in[1];
    const float* u = (const float*)d_in[2];
    float* out = (float*)d_out;
    unsigned short* wb = (unsigned short*)d_ws;   // 512*4096*2 = 4 MB

    binarize_kernel<<<dim3(N_DIM * K_DIM / 4 / 256), dim3(256), 0, stream>>>(w, u, wb);

    dim3 grid(N_DIM / BN, M_DIM / BM);            // (4, 128)
    gemm_bin_kernel<<<grid, dim3(256), 0, stream>>>(x, wb, out);
}